// Round 11
// baseline (154.336 us; speedup 1.0000x reference)
//
#include <hip/hip_runtime.h>
#include <hip/hip_bf16.h>
#include <stdint.h>
#include <stddef.h>

// MMD via single signed 2N x 2N RBF gram, lower triangle only.
// Round 11: r10 structure (MX-fp8 16x16x128 unit scales, 128x64 tiles,
// 16 KB ping-pong LDS, 1 barrier/tile) + EXPLICIT epilogue/MFMA overlap:
// acc double-buffer (accA/accB, wave-uniform phase flag), tile t's exp2
// epilogue (~450 cyc VALU) executes right after tile t+1's 8 MFMAs issue
// (~256 cyc matrix pipe) -> both pipes busy within one wave. r9/r10 showed
// pipes serialize otherwise (TLP didn't help; dur == sum of pipe times).
// Addressing VALU trimmed: ds offsets + staging offsets precomputed.

#define N_PTS   8192
#define DIM     256
#define TWO_N   16384
#define CS2     16

#define AS1 __attribute__((address_space(1)))
#define AS3 __attribute__((address_space(3)))

typedef __attribute__((ext_vector_type(4))) float f32x4;
typedef __attribute__((ext_vector_type(4))) int   i32x4;
typedef __attribute__((ext_vector_type(8))) int   i32x8;

// ---------------------------------------------------------------------------
// Prep: fp32 -> fp8 e4m3 (row-major) + c2-scaled fp32 row norms + zero output.
// ---------------------------------------------------------------------------
__global__ __launch_bounds__(256) void mmd_prep(const float* __restrict__ X,
                                                const float* __restrict__ Y,
                                                const int* __restrict__ sigmap,
                                                unsigned char* __restrict__ Zf8,
                                                float* __restrict__ n2,
                                                float* __restrict__ out) {
    if (blockIdx.x == 0 && threadIdx.x == 0) out[0] = 0.0f;

    const int wave = threadIdx.x >> 6;
    const int lane = threadIdx.x & 63;
    const int row  = blockIdx.x * 4 + wave;

    const float* src = (row < N_PTS) ? (X + (size_t)row * DIM)
                                     : (Y + (size_t)(row - N_PTS) * DIM);
    float4 v = ((const float4*)src)[lane];

    float s = v.x * v.x + v.y * v.y + v.z * v.z + v.w * v.w;
#pragma unroll
    for (int off = 32; off; off >>= 1) s += __shfl_down(s, off, 64);
    if (lane == 0) {
        const float c2 = -1.4426950408889634f / (float)(*sigmap);
        n2[row] = c2 * s;
    }

    const int p01 = __builtin_amdgcn_cvt_pk_fp8_f32(v.x, v.y, 0, false);
    const int p23 = __builtin_amdgcn_cvt_pk_fp8_f32(v.z, v.w, 0, false);
    const unsigned int pk = ((unsigned)p01 & 0xffffu) | ((unsigned)p23 << 16);
    *(unsigned int*)(Zf8 + (size_t)row * DIM + (size_t)lane * 4) = pk;
}

// ---------------------------------------------------------------------------
__global__ __launch_bounds__(256, 2) void mmd_main(const unsigned char* __restrict__ Zf8,
                                                   const float* __restrict__ n2,
                                                   const int* __restrict__ sigmap,
                                                   float* __restrict__ out) {
    __shared__ char smem_b[32768];   // 2 x 16 KB B-tile buffers, XOR swizzle
    __shared__ float n2rS[128];
    __shared__ float wsum[4];

    const int bid = (int)blockIdx.x;
    const int br  = 127 - (bid >> 4);
    const int cs  = bid & (CS2 - 1);
    const int bcMax = 2 * br + 1;
    if (cs > bcMax) return;

    const int t    = threadIdx.x;
    const int wave = t >> 6;
    const int lane = t & 63;
    const int wm   = wave >> 1;
    const int wn   = wave & 1;
    const int g    = lane >> 4;
    const int ml   = lane & 15;
    const int rowBase = br * 128;
    const int brX  = (br < 64);

    const float m2 = 2.8853900817779268f / (float)(*sigmap);   // -2*c2
    const int   SC = 0x7f7f7f7f;                               // unit E8M0 scales

    // ---- precomputed staging offsets (4 chunks / thread) ----
    int g_off[4], l_off[4];
#pragma unroll
    for (int i = 0; i < 4; ++i) {
        const int cidx = i * 256 + t;
        const int col  = cidx >> 4;
        const int s    = cidx & 15;
        const int gc   = s ^ (col & 15);
        g_off[i] = col * DIM + gc * 16;
        l_off[i] = cidx * 16;
    }

    // ---- precomputed B-fragment LDS offsets [kc][nt][half] ----
    int bfo[2][2][2];
#pragma unroll
    for (int kc = 0; kc < 2; ++kc) {
        const int j0 = kc * 8 + g * 2;
#pragma unroll
        for (int nt = 0; nt < 2; ++nt) {
            const int col = wn * 32 + nt * 16 + ml;
            bfo[kc][nt][0] = col * 256 + ((j0)     ^ (col & 15)) * 16;
            bfo[kc][nt][1] = col * 256 + ((j0 + 1) ^ (col & 15)) * 16;
        }
    }

    // ---- stage tile 0 into buffer 0 ----
    {
        const unsigned char* base = Zf8 + (size_t)(cs * 64) * DIM;
#pragma unroll
        for (int i = 0; i < 4; ++i)
            __builtin_amdgcn_global_load_lds((const AS1 void*)(base + g_off[i]),
                                             (AS3 void*)(smem_b + l_off[i]), 16, 0, 0);
    }
    if (t < 128) n2rS[t] = n2[rowBase + t];

    // ---- A fragments (full K=256, this wave's 64 rows): 64 VGPRs ----
    i32x8 af[4][2];
#pragma unroll
    for (int mt = 0; mt < 4; ++mt) {
        const unsigned char* rp =
            Zf8 + (size_t)(rowBase + wm * 64 + mt * 16 + ml) * DIM + g * 32;
#pragma unroll
        for (int kc = 0; kc < 2; ++kc) {
            union { i32x4 h[2]; i32x8 v; } u;
            u.h[0] = *(const i32x4*)(rp + kc * 128);
            u.h[1] = *(const i32x4*)(rp + kc * 128 + 16);
            af[mt][kc] = u.v;
        }
    }

    f32x4 accA[4][2], accB[4][2];
    float block_acc = 0.0f;

#define ZERO_ACC(ACC)                                                         \
    {                                                                         \
        _Pragma("unroll") for (int mt = 0; mt < 4; ++mt)                      \
            _Pragma("unroll") for (int nt = 0; nt < 2; ++nt)                  \
                ACC[mt][nt] = (f32x4){0.f, 0.f, 0.f, 0.f};                    \
    }

#define COMPUTE(ACC, BUFR)                                                    \
    {                                                                         \
        _Pragma("unroll") for (int kc = 0; kc < 2; ++kc) {                    \
            i32x8 bf[2];                                                      \
            _Pragma("unroll") for (int nt = 0; nt < 2; ++nt) {                \
                union { i32x4 h[2]; i32x8 v; } u;                             \
                u.h[0] = *(const i32x4*)((BUFR) + bfo[kc][nt][0]);            \
                u.h[1] = *(const i32x4*)((BUFR) + bfo[kc][nt][1]);            \
                bf[nt] = u.v;                                                 \
            }                                                                 \
            _Pragma("unroll") for (int mt = 0; mt < 4; ++mt)                  \
                _Pragma("unroll") for (int nt = 0; nt < 2; ++nt)              \
                    ACC[mt][nt] = __builtin_amdgcn_mfma_scale_f32_16x16x128_f8f6f4( \
                        af[mt][kc], bf[nt], ACC[mt][nt], 0, 0, 0, SC, 0, SC); \
        }                                                                     \
    }

#define EPILOGUE(ACC, B0, B1, W)                                              \
    {                                                                         \
        float t0 = 0.f, t1 = 0.f, t2 = 0.f, t3 = 0.f;                         \
        _Pragma("unroll") for (int mt = 0; mt < 4; ++mt) {                    \
            const f32x4 ar = *(const f32x4*)&n2rS[wm * 64 + mt * 16 + g * 4]; \
            {                                                                 \
                t0 += __builtin_amdgcn_exp2f(fmaf(ACC[mt][0][0], m2, ar[0] + (B0))); \
                t1 += __builtin_amdgcn_exp2f(fmaf(ACC[mt][0][1], m2, ar[1] + (B0))); \
                t2 += __builtin_amdgcn_exp2f(fmaf(ACC[mt][0][2], m2, ar[2] + (B0))); \
                t3 += __builtin_amdgcn_exp2f(fmaf(ACC[mt][0][3], m2, ar[3] + (B0))); \
                t0 += __builtin_amdgcn_exp2f(fmaf(ACC[mt][1][0], m2, ar[0] + (B1))); \
                t1 += __builtin_amdgcn_exp2f(fmaf(ACC[mt][1][1], m2, ar[1] + (B1))); \
                t2 += __builtin_amdgcn_exp2f(fmaf(ACC[mt][1][2], m2, ar[2] + (B1))); \
                t3 += __builtin_amdgcn_exp2f(fmaf(ACC[mt][1][3], m2, ar[3] + (B1))); \
            }                                                                 \
        }                                                                     \
        block_acc = fmaf((W), (t0 + t1) + (t2 + t3), block_acc);              \
    }

#define WEIGHT(BC) ((((BC) < 128) == brX ? 1.0f : -1.0f) * ((BC) < 2 * br ? 2.0f : 1.0f))

    const char* bufR = smem_b;
    char*       bufW = smem_b + 16384;

    // ---- prologue: tile cs into accA ----
    float pB0 = n2[cs * 64 + wn * 32 + ml];
    float pB1 = n2[cs * 64 + wn * 32 + 16 + ml];
    float pW  = WEIGHT(cs);

    __syncthreads();                       // tile cs staged
    if (cs + CS2 <= bcMax) {
        const unsigned char* base = Zf8 + (size_t)((cs + CS2) * 64) * DIM;
#pragma unroll
        for (int i = 0; i < 4; ++i)
            __builtin_amdgcn_global_load_lds((const AS1 void*)(base + g_off[i]),
                                             (AS3 void*)(bufW + l_off[i]), 16, 0, 0);
    }
    ZERO_ACC(accA);
    COMPUTE(accA, bufR);

    bool pendA = true;                     // accA holds the pending epilogue
    for (int bc = cs + CS2; bc <= bcMax; bc += CS2) {
        const float cB0 = n2[bc * 64 + wn * 32 + ml];
        const float cB1 = n2[bc * 64 + wn * 32 + 16 + ml];

        { const char* tmp = bufR; bufR = bufW; bufW = (char*)tmp; }

        __syncthreads();                   // tile bc staged in bufR
        if (bc + CS2 <= bcMax) {
            const unsigned char* base = Zf8 + (size_t)((bc + CS2) * 64) * DIM;
#pragma unroll
            for (int i = 0; i < 4; ++i)
                __builtin_amdgcn_global_load_lds((const AS1 void*)(base + g_off[i]),
                                                 (AS3 void*)(bufW + l_off[i]), 16, 0, 0);
        }

        if (pendA) {                       // wave-uniform; no divergence
            ZERO_ACC(accB);
            COMPUTE(accB, bufR);           // MFMAs issue first (matrix pipe)
            EPILOGUE(accA, pB0, pB1, pW);  // prev tile's exp2 overlaps them
        } else {
            ZERO_ACC(accA);
            COMPUTE(accA, bufR);
            EPILOGUE(accB, pB0, pB1, pW);
        }
        pendA = !pendA;
        pB0 = cB0; pB1 = cB1; pW = WEIGHT(bc);
    }

    if (pendA) { EPILOGUE(accA, pB0, pB1, pW); }
    else       { EPILOGUE(accB, pB0, pB1, pW); }

    // ---- block reduction + single atomic ----
    float s = block_acc;
#pragma unroll
    for (int off = 32; off; off >>= 1) s += __shfl_down(s, off, 64);
    if (lane == 0) wsum[wave] = s;
    __syncthreads();
    if (t == 0)
        atomicAdd(out, (wsum[0] + wsum[1] + wsum[2] + wsum[3]) * (1.0f / 67108864.0f));
}

// ---------------------------------------------------------------------------
extern "C" void kernel_launch(void* const* d_in, const int* in_sizes, int n_in,
                              void* d_out, int out_size, void* d_ws, size_t ws_size,
                              hipStream_t stream) {
    const float* X      = (const float*)d_in[0];
    const float* Y      = (const float*)d_in[1];
    const int*   sigmap = (const int*)d_in[2];
    float*       out    = (float*)d_out;

    unsigned char* Zf8 = (unsigned char*)d_ws;                        // 4 MB
    float*         n2  = (float*)((char*)d_ws + (size_t)TWO_N * DIM);

    mmd_prep<<<TWO_N / 4, 256, 0, stream>>>(X, Y, sigmap, Zf8, n2, out);
    mmd_main<<<128 * CS2, 256, 0, stream>>>(Zf8, n2, sigmap, out);
}